// Round 2
// baseline (427.555 us; speedup 1.0000x reference)
//
#include <hip/hip_runtime.h>
#include <stdint.h>

#define NB 4
#define NS 2048
#define NE 1024
#define NH 16
#define ND 64

typedef __attribute__((ext_vector_type(8))) short short8;
typedef __attribute__((ext_vector_type(4))) float f32x4;
typedef __attribute__((ext_vector_type(4))) unsigned short us4;

__device__ __forceinline__ unsigned short f2bf(float f) {
    unsigned u = __builtin_bit_cast(unsigned, f);
    u += 0x7FFFu + ((u >> 16) & 1u);   // round-to-nearest-even
    return (unsigned short)(u >> 16);
}

// ---------------- weight fp32 -> bf16 convert (1M elems per launch) ----------------
__global__ __launch_bounds__(256) void cvt_w_kernel(const float* __restrict__ src,
                                                    unsigned short* __restrict__ dst) {
    int i = (blockIdx.x * 256 + threadIdx.x) * 4;
    f32x4 f = *(const f32x4*)(src + i);
    us4 o;
#pragma unroll
    for (int j = 0; j < 4; ++j) o[j] = f2bf(f[j]);
    *(us4*)(dst + i) = o;
}

// ---------------- GEMM: C[M,N] = A[M,K] @ W[N,K]^T ----------------
// M=8192, N=1024, K=1024. 128x128 tile, BK=32, 4 waves (each 64x64).
// A_IS_F32: A is fp32 (converted to bf16 during LDS staging), else bf16.
// OUT_MODE 0: write bf16 to [B,H,S,D] head-major layout (n = h*64+d).
// OUT_MODE 1: write fp32 to [M,N] with bias add.
template<int A_IS_F32, int OUT_MODE>
__global__ __launch_bounds__(256) void gemm_bt(const void* __restrict__ Aptr,
                                               const unsigned short* __restrict__ Wp,
                                               void* __restrict__ Cp,
                                               const float* __restrict__ bias) {
    constexpr int K = 1024;
    __shared__ unsigned short As[128][40];  // pad 32->40: row stride 20 dwords -> 2-way (free)
    __shared__ unsigned short Bs[128][40];
    const int tid = threadIdx.x;
    const int bm = blockIdx.x, bn = blockIdx.y;
    const int lane = tid & 63, wid = tid >> 6;
    const int lr = lane & 15, lg = lane >> 4;
    const int wr = wid >> 1, wc = wid & 1;
    const int srow = tid >> 1, shalf = tid & 1;

    f32x4 acc[4][4];
#pragma unroll
    for (int a = 0; a < 4; ++a)
#pragma unroll
        for (int b = 0; b < 4; ++b) acc[a][b] = (f32x4){0.f, 0.f, 0.f, 0.f};

    const size_t arow = (size_t)(bm * 128 + srow) * K + shalf * 16;
    const size_t brow = (size_t)(bn * 128 + srow) * K + shalf * 16;

    for (int k0 = 0; k0 < K; k0 += 32) {
        __syncthreads();  // protect previous iteration's fragment reads
        if (A_IS_F32) {
            const float* ap = (const float*)Aptr + arow + k0;
            f32x4 a0 = *(const f32x4*)(ap);
            f32x4 a1 = *(const f32x4*)(ap + 4);
            f32x4 a2 = *(const f32x4*)(ap + 8);
            f32x4 a3 = *(const f32x4*)(ap + 12);
            short8 p0, p1;
#pragma unroll
            for (int j = 0; j < 4; ++j) {
                p0[j]     = (short)f2bf(a0[j]);
                p0[j + 4] = (short)f2bf(a1[j]);
                p1[j]     = (short)f2bf(a2[j]);
                p1[j + 4] = (short)f2bf(a3[j]);
            }
            *(short8*)&As[srow][shalf * 16]     = p0;
            *(short8*)&As[srow][shalf * 16 + 8] = p1;
        } else {
            const unsigned short* ap = (const unsigned short*)Aptr + arow + k0;
            short8 a0 = *(const short8*)(ap);
            short8 a1 = *(const short8*)(ap + 8);
            *(short8*)&As[srow][shalf * 16]     = a0;
            *(short8*)&As[srow][shalf * 16 + 8] = a1;
        }
        {
            const unsigned short* bp = Wp + brow + k0;
            short8 b0 = *(const short8*)(bp);
            short8 b1 = *(const short8*)(bp + 8);
            *(short8*)&Bs[srow][shalf * 16]     = b0;
            *(short8*)&Bs[srow][shalf * 16 + 8] = b1;
        }
        __syncthreads();

        short8 af[4], bfr[4];
#pragma unroll
        for (int mi = 0; mi < 4; ++mi) af[mi]  = *(const short8*)&As[wr * 64 + mi * 16 + lr][lg * 8];
#pragma unroll
        for (int ni = 0; ni < 4; ++ni) bfr[ni] = *(const short8*)&Bs[wc * 64 + ni * 16 + lr][lg * 8];
#pragma unroll
        for (int mi = 0; mi < 4; ++mi)
#pragma unroll
            for (int ni = 0; ni < 4; ++ni)
                acc[mi][ni] = __builtin_amdgcn_mfma_f32_16x16x32_bf16(af[mi], bfr[ni], acc[mi][ni], 0, 0, 0);
    }

#pragma unroll
    for (int mi = 0; mi < 4; ++mi) {
#pragma unroll
        for (int ni = 0; ni < 4; ++ni) {
            const int n = bn * 128 + wc * 64 + ni * 16 + lr;
#pragma unroll
            for (int i = 0; i < 4; ++i) {
                const int m = bm * 128 + wr * 64 + mi * 16 + lg * 4 + i;
                const float val = acc[mi][ni][i];
                if (OUT_MODE == 0) {
                    const int b = m >> 11, s = m & 2047, h = n >> 6, d = n & 63;
                    ((unsigned short*)Cp)[(((size_t)b * NH + h) * NS + s) * ND + d] = f2bf(val);
                } else {
                    ((float*)Cp)[(size_t)m * 1024 + n] = val + bias[n];
                }
            }
        }
    }
}

// ---------------- flash attention ----------------
// grid (S/64, B*H), 256 threads. Wave w handles q rows q0+w*16 .. +15.
// q/k/v layout: [B,H,S,D] bf16. Output: [B,S,H,D] bf16, scaled by 0.125/l.
__global__ __launch_bounds__(256) void attn_kernel(const unsigned short* __restrict__ q,
                                                   const unsigned short* __restrict__ k,
                                                   const unsigned short* __restrict__ v,
                                                   unsigned short* __restrict__ o) {
    __shared__ unsigned short Kl[64][72];      // pad: stride 36 dwords -> 2-way (free)
    __shared__ unsigned short Vt[64][72];      // V transposed: Vt[d][kv]
    __shared__ unsigned short Pl[4][16][72];   // per-wave P round-trip
    const int tid = threadIdx.x;
    const int lane = tid & 63, wid = tid >> 6;
    const int lr = lane & 15, lg = lane >> 4;
    const int bh = blockIdx.y;
    const int q0 = blockIdx.x * 64;
    const size_t base = (size_t)bh * NS * ND;

    // Q fragments held in registers (A-operand: row=lane&15, k = lg*8+e)
    short8 qf0, qf1;
    {
        const unsigned short* qp = q + base + (size_t)(q0 + wid * 16 + lr) * ND + lg * 8;
        qf0 = *(const short8*)(qp);
        qf1 = *(const short8*)(qp + 32);
    }

    float m_run[4], l_run[4];
    f32x4 oa[4];
#pragma unroll
    for (int i = 0; i < 4; ++i) { m_run[i] = -__builtin_inff(); l_run[i] = 0.f; }
#pragma unroll
    for (int n = 0; n < 4; ++n) oa[n] = (f32x4){0.f, 0.f, 0.f, 0.f};

    const int sr = tid >> 2, sc = tid & 3;  // staging: row 0..63, quarter 0..3

    for (int kv0 = 0; kv0 < NS; kv0 += 64) {
        __syncthreads();
        {
            const unsigned short* kp = k + base + (size_t)(kv0 + sr) * ND + sc * 16;
            short8 k0v = *(const short8*)(kp);
            short8 k1v = *(const short8*)(kp + 8);
            *(short8*)&Kl[sr][sc * 16]     = k0v;
            *(short8*)&Kl[sr][sc * 16 + 8] = k1v;
            const unsigned short* vp = v + base + (size_t)(kv0 + sr) * ND + sc * 16;
            short8 v0v = *(const short8*)(vp);
            short8 v1v = *(const short8*)(vp + 8);
#pragma unroll
            for (int j = 0; j < 8; ++j) Vt[sc * 16 + j][sr]     = (unsigned short)v0v[j];
#pragma unroll
            for (int j = 0; j < 8; ++j) Vt[sc * 16 + 8 + j][sr] = (unsigned short)v1v[j];
        }
        __syncthreads();

        // S = Q K^T  (per wave: 16 q x 64 kv)
        f32x4 st[4];
#pragma unroll
        for (int t = 0; t < 4; ++t) st[t] = (f32x4){0.f, 0.f, 0.f, 0.f};
#pragma unroll
        for (int t = 0; t < 4; ++t) {
            short8 kf0 = *(const short8*)&Kl[t * 16 + lr][lg * 8];
            short8 kf1 = *(const short8*)&Kl[t * 16 + lr][32 + lg * 8];
            st[t] = __builtin_amdgcn_mfma_f32_16x16x32_bf16(qf0, kf0, st[t], 0, 0, 0);
            st[t] = __builtin_amdgcn_mfma_f32_16x16x32_bf16(qf1, kf1, st[t], 0, 0, 0);
        }

        // online softmax: row r = lg*4+i, kv col = t*16 + lr; reduce over 16 lanes
        float pm[4];
#pragma unroll
        for (int i = 0; i < 4; ++i)
            pm[i] = fmaxf(fmaxf(st[0][i], st[1][i]), fmaxf(st[2][i], st[3][i]));
#pragma unroll
        for (int off = 1; off < 16; off <<= 1) {
#pragma unroll
            for (int i = 0; i < 4; ++i)
                pm[i] = fmaxf(pm[i], __shfl_xor(pm[i], off, 64));
        }
        float alpha[4], rs[4];
#pragma unroll
        for (int i = 0; i < 4; ++i) {
            float mn = fmaxf(m_run[i], pm[i]);
            alpha[i] = __expf(m_run[i] - mn);
            m_run[i] = mn;
            rs[i] = 0.f;
        }
#pragma unroll
        for (int t = 0; t < 4; ++t)
#pragma unroll
            for (int i = 0; i < 4; ++i) {
                float p = __expf(st[t][i] - m_run[i]);
                st[t][i] = p;
                rs[i] += p;
            }
#pragma unroll
        for (int off = 1; off < 16; off <<= 1) {
#pragma unroll
            for (int i = 0; i < 4; ++i)
                rs[i] += __shfl_xor(rs[i], off, 64);
        }
#pragma unroll
        for (int i = 0; i < 4; ++i) l_run[i] = l_run[i] * alpha[i] + rs[i];
#pragma unroll
        for (int n = 0; n < 4; ++n)
#pragma unroll
            for (int i = 0; i < 4; ++i) oa[n][i] *= alpha[i];

        // P (C-layout) -> per-wave LDS -> A-fragment layout
#pragma unroll
        for (int t = 0; t < 4; ++t)
#pragma unroll
            for (int i = 0; i < 4; ++i)
                Pl[wid][lg * 4 + i][t * 16 + lr] = f2bf(st[t][i]);
        asm volatile("s_waitcnt lgkmcnt(0)" ::: "memory");  // wave-local RAW through LDS
        short8 pf0 = *(const short8*)&Pl[wid][lr][lg * 8];
        short8 pf1 = *(const short8*)&Pl[wid][lr][32 + lg * 8];
#pragma unroll
        for (int n = 0; n < 4; ++n) {
            short8 vf0 = *(const short8*)&Vt[n * 16 + lr][lg * 8];
            short8 vf1 = *(const short8*)&Vt[n * 16 + lr][32 + lg * 8];
            oa[n] = __builtin_amdgcn_mfma_f32_16x16x32_bf16(pf0, vf0, oa[n], 0, 0, 0);
            oa[n] = __builtin_amdgcn_mfma_f32_16x16x32_bf16(pf1, vf1, oa[n], 0, 0, 0);
        }
    }

    const int b = bh >> 4, h = bh & 15;
    float scl[4];
#pragma unroll
    for (int i = 0; i < 4; ++i) scl[i] = 0.125f / l_run[i];  // softmax BEFORE scaling -> /8 here
#pragma unroll
    for (int n = 0; n < 4; ++n) {
#pragma unroll
        for (int i = 0; i < 4; ++i) {
            const int s = q0 + wid * 16 + lg * 4 + i;
            const int d = n * 16 + lr;
            o[(((size_t)b * NS + s) * NH + h) * ND + d] = f2bf(oa[n][i] * scl[i]);
        }
    }
}

extern "C" void kernel_launch(void* const* d_in, const int* in_sizes, int n_in,
                              void* d_out, int out_size, void* d_ws, size_t ws_size,
                              hipStream_t stream) {
    (void)in_sizes; (void)n_in; (void)out_size; (void)ws_size;
    const float* values  = (const float*)d_in[0];
    const float* keys    = (const float*)d_in[1];
    const float* queries = (const float*)d_in[2];
    const float* Wv = (const float*)d_in[3];
    const float* Wk = (const float*)d_in[4];
    const float* Wq = (const float*)d_in[5];
    const float* Wo = (const float*)d_in[6];
    const float* bo = (const float*)d_in[7];

    uint8_t* ws = (uint8_t*)d_ws;
    const size_t MB = (size_t)1 << 20;
    unsigned short* wvb = (unsigned short*)(ws + 0 * MB);
    unsigned short* wkb = (unsigned short*)(ws + 2 * MB);
    unsigned short* wqb = (unsigned short*)(ws + 4 * MB);
    unsigned short* wob = (unsigned short*)(ws + 6 * MB);
    unsigned short* qb  = (unsigned short*)(ws + 8 * MB);   // [B,H,S,D] bf16, 16 MB
    unsigned short* kb  = (unsigned short*)(ws + 24 * MB);
    unsigned short* vb  = (unsigned short*)(ws + 40 * MB);
    unsigned short* ab  = (unsigned short*)(ws + 56 * MB);  // [B,S,H,D] bf16, 16 MB

    cvt_w_kernel<<<1024, 256, 0, stream>>>(Wv, wvb);
    cvt_w_kernel<<<1024, 256, 0, stream>>>(Wk, wkb);
    cvt_w_kernel<<<1024, 256, 0, stream>>>(Wq, wqb);

    dim3 gg(64, 8);  // (M/128, N/128)
    gemm_bt<1, 0><<<gg, 256, 0, stream>>>(queries, wqb, qb, nullptr);
    gemm_bt<1, 0><<<gg, 256, 0, stream>>>(keys,    wkb, kb, nullptr);
    gemm_bt<1, 0><<<gg, 256, 0, stream>>>(values,  wvb, vb, nullptr);

    cvt_w_kernel<<<1024, 256, 0, stream>>>(Wo, wob);

    attn_kernel<<<dim3(32, 64), 256, 0, stream>>>(qb, kb, vb, ab);

    gemm_bt<0, 1><<<gg, 256, 0, stream>>>(ab, wob, d_out, bo);
}

// Round 3
// 425.756 us; speedup vs baseline: 1.0042x; 1.0042x over previous
//
#include <hip/hip_runtime.h>
#include <stdint.h>

#define NB 4
#define NS 2048
#define NE 1024
#define NH 16
#define ND 64

typedef __attribute__((ext_vector_type(8))) short short8;
typedef __attribute__((ext_vector_type(4))) float f32x4;
typedef __attribute__((ext_vector_type(4))) unsigned short us4;

__device__ __forceinline__ unsigned short f2bf(float f) {
    unsigned u = __builtin_bit_cast(unsigned, f);
    u += 0x7FFFu + ((u >> 16) & 1u);   // round-to-nearest-even
    return (unsigned short)(u >> 16);
}

// ---------------- weight fp32 -> bf16 convert (1M elems per launch) ----------------
__global__ __launch_bounds__(256) void cvt_w_kernel(const float* __restrict__ src,
                                                    unsigned short* __restrict__ dst) {
    int i = (blockIdx.x * 256 + threadIdx.x) * 4;
    f32x4 f = *(const f32x4*)(src + i);
    us4 o;
#pragma unroll
    for (int j = 0; j < 4; ++j) o[j] = f2bf(f[j]);
    *(us4*)(dst + i) = o;
}

// ---------------- GEMM: C[M,N] = A[M,K] @ W[N,K]^T ----------------
// M=8192, N=1024, K=1024. 128x128 tile, BK=32, 4 waves (each 64x64).
// A_IS_F32: A is fp32 (converted to bf16 during LDS staging), else bf16.
// OUT_MODE 0: write bf16 to [B,H,S,D] head-major layout (n = h*64+d).
// OUT_MODE 1: write fp32 to [M,N] with bias add.
// OUT_MODE 2: write bf16 TRANSPOSED per head: [B,H,D,S] (for V), packed us4.
template<int A_IS_F32, int OUT_MODE>
__global__ __launch_bounds__(256) void gemm_bt(const void* __restrict__ Aptr,
                                               const unsigned short* __restrict__ Wp,
                                               void* __restrict__ Cp,
                                               const float* __restrict__ bias) {
    constexpr int K = 1024;
    __shared__ unsigned short As[128][40];  // pad 32->40: row stride 20 dwords -> 2-way (free)
    __shared__ unsigned short Bs[128][40];
    const int tid = threadIdx.x;
    const int bm = blockIdx.x, bn = blockIdx.y;
    const int lane = tid & 63, wid = tid >> 6;
    const int lr = lane & 15, lg = lane >> 4;
    const int wr = wid >> 1, wc = wid & 1;
    const int srow = tid >> 1, shalf = tid & 1;

    f32x4 acc[4][4];
#pragma unroll
    for (int a = 0; a < 4; ++a)
#pragma unroll
        for (int b = 0; b < 4; ++b) acc[a][b] = (f32x4){0.f, 0.f, 0.f, 0.f};

    const size_t arow = (size_t)(bm * 128 + srow) * K + shalf * 16;
    const size_t brow = (size_t)(bn * 128 + srow) * K + shalf * 16;

    for (int k0 = 0; k0 < K; k0 += 32) {
        __syncthreads();  // protect previous iteration's fragment reads
        if (A_IS_F32) {
            const float* ap = (const float*)Aptr + arow + k0;
            f32x4 a0 = *(const f32x4*)(ap);
            f32x4 a1 = *(const f32x4*)(ap + 4);
            f32x4 a2 = *(const f32x4*)(ap + 8);
            f32x4 a3 = *(const f32x4*)(ap + 12);
            short8 p0, p1;
#pragma unroll
            for (int j = 0; j < 4; ++j) {
                p0[j]     = (short)f2bf(a0[j]);
                p0[j + 4] = (short)f2bf(a1[j]);
                p1[j]     = (short)f2bf(a2[j]);
                p1[j + 4] = (short)f2bf(a3[j]);
            }
            *(short8*)&As[srow][shalf * 16]     = p0;
            *(short8*)&As[srow][shalf * 16 + 8] = p1;
        } else {
            const unsigned short* ap = (const unsigned short*)Aptr + arow + k0;
            short8 a0 = *(const short8*)(ap);
            short8 a1 = *(const short8*)(ap + 8);
            *(short8*)&As[srow][shalf * 16]     = a0;
            *(short8*)&As[srow][shalf * 16 + 8] = a1;
        }
        {
            const unsigned short* bp = Wp + brow + k0;
            short8 b0 = *(const short8*)(bp);
            short8 b1 = *(const short8*)(bp + 8);
            *(short8*)&Bs[srow][shalf * 16]     = b0;
            *(short8*)&Bs[srow][shalf * 16 + 8] = b1;
        }
        __syncthreads();

        short8 af[4], bfr[4];
#pragma unroll
        for (int mi = 0; mi < 4; ++mi) af[mi]  = *(const short8*)&As[wr * 64 + mi * 16 + lr][lg * 8];
#pragma unroll
        for (int ni = 0; ni < 4; ++ni) bfr[ni] = *(const short8*)&Bs[wc * 64 + ni * 16 + lr][lg * 8];
#pragma unroll
        for (int mi = 0; mi < 4; ++mi)
#pragma unroll
            for (int ni = 0; ni < 4; ++ni)
                acc[mi][ni] = __builtin_amdgcn_mfma_f32_16x16x32_bf16(af[mi], bfr[ni], acc[mi][ni], 0, 0, 0);
    }

#pragma unroll
    for (int mi = 0; mi < 4; ++mi) {
#pragma unroll
        for (int ni = 0; ni < 4; ++ni) {
            const int n = bn * 128 + wc * 64 + ni * 16 + lr;
            if (OUT_MODE == 2) {
                // V: write [B,H,D,S]; i -> s consecutive, pack 4 bf16 into one 8B store.
                const int m0 = bm * 128 + wr * 64 + mi * 16 + lg * 4;
                const int b = m0 >> 11, s0 = m0 & 2047;
                const int h = n >> 6, d = n & 63;
                us4 pk;
#pragma unroll
                for (int i = 0; i < 4; ++i) pk[i] = f2bf(acc[mi][ni][i]);
                *(us4*)&((unsigned short*)Cp)[(((size_t)b * NH + h) * ND + d) * NS + s0] = pk;
            } else {
#pragma unroll
                for (int i = 0; i < 4; ++i) {
                    const int m = bm * 128 + wr * 64 + mi * 16 + lg * 4 + i;
                    const float val = acc[mi][ni][i];
                    if (OUT_MODE == 0) {
                        const int b = m >> 11, s = m & 2047, h = n >> 6, d = n & 63;
                        ((unsigned short*)Cp)[(((size_t)b * NH + h) * NS + s) * ND + d] = f2bf(val);
                    } else {
                        ((float*)Cp)[(size_t)m * 1024 + n] = val + bias[n];
                    }
                }
            }
        }
    }
}

// ---------------- flash attention (swapped-operand form) ----------------
// grid (S/64, B*H), 256 threads, wave w owns q rows q0+w*16..+15.
// q,k layout: [B,H,S,D] bf16. vt layout: [B,H,D,S] bf16 (pre-transposed).
// Every lane's softmax state belongs to the single q-row q = lane&15:
//   S^T = mfma(K_frag, Q_frag):  C col = q = lane&15, row = kv = t*16 + (lane>>4)*4 + i
//   O^T = mfma(Vt_frag, P^T_frag): C col = q = lane&15, row = d = n*16 + (lane>>4)*4 + i
// V fragments are loaded straight from global (L1/L2-resident: 256KB/head) - no V LDS.
__global__ __launch_bounds__(256) void attn_kernel(const unsigned short* __restrict__ q,
                                                   const unsigned short* __restrict__ k,
                                                   const unsigned short* __restrict__ vt,
                                                   unsigned short* __restrict__ o) {
    __shared__ unsigned short Kl[64][72];      // K tile [kv][d], pad 72
    __shared__ unsigned short Pl[4][16][72];   // per-wave P [q][kv]
    const int tid = threadIdx.x;
    const int lane = tid & 63, wid = tid >> 6;
    const int lr = lane & 15, lg = lane >> 4;
    const int bh = blockIdx.y;
    const int q0 = blockIdx.x * 64;
    const size_t base = (size_t)bh * NS * ND;   // same offset for q/k ([B,H,S,D]) and vt ([B,H,D,S])

    // Q fragment (A- and B-operand lane maps coincide): q row = q0+wid*16+lr, k = d
    short8 qf0, qf1;
    {
        const unsigned short* qp = q + base + (size_t)(q0 + wid * 16 + lr) * ND + lg * 8;
        qf0 = *(const short8*)(qp);
        qf1 = *(const short8*)(qp + 32);
    }

    float m_run = -__builtin_inff(), l_run = 0.f;   // state for q = lr (replicated over lg)
    f32x4 oa[4];
#pragma unroll
    for (int n = 0; n < 4; ++n) oa[n] = (f32x4){0.f, 0.f, 0.f, 0.f};

    const int sr = tid >> 2, sc = tid & 3;

    for (int kv0 = 0; kv0 < NS; kv0 += 64) {
        __syncthreads();
        {   // stage K tile [64 kv][64 d]
            const unsigned short* kp = k + base + (size_t)(kv0 + sr) * ND + sc * 16;
            short8 k0v = *(const short8*)(kp);
            short8 k1v = *(const short8*)(kp + 8);
            *(short8*)&Kl[sr][sc * 16]     = k0v;
            *(short8*)&Kl[sr][sc * 16 + 8] = k1v;
        }
        __syncthreads();

        // issue V fragment loads early (independent of K/P) to hide L2 latency
        short8 vf0[4], vf1[4];
#pragma unroll
        for (int n = 0; n < 4; ++n) {
            const unsigned short* vr = vt + base + (size_t)(n * 16 + lr) * NS + kv0 + lg * 8;
            vf0[n] = *(const short8*)(vr);
            vf1[n] = *(const short8*)(vr + 32);
        }

        // S^T = K·Q^T : per lane 16 kv values for its own q-row
        f32x4 st[4];
#pragma unroll
        for (int t = 0; t < 4; ++t) st[t] = (f32x4){0.f, 0.f, 0.f, 0.f};
#pragma unroll
        for (int t = 0; t < 4; ++t) {
            short8 kf0 = *(const short8*)&Kl[t * 16 + lr][lg * 8];
            short8 kf1 = *(const short8*)&Kl[t * 16 + lr][32 + lg * 8];
            st[t] = __builtin_amdgcn_mfma_f32_16x16x32_bf16(kf0, qf0, st[t], 0, 0, 0);
            st[t] = __builtin_amdgcn_mfma_f32_16x16x32_bf16(kf1, qf1, st[t], 0, 0, 0);
        }

        // online softmax (scalar state, 2 shfl per reduction)
        float pm = st[0][0];
#pragma unroll
        for (int t = 0; t < 4; ++t)
#pragma unroll
            for (int i = 0; i < 4; ++i) pm = fmaxf(pm, st[t][i]);
        pm = fmaxf(pm, __shfl_xor(pm, 16, 64));
        pm = fmaxf(pm, __shfl_xor(pm, 32, 64));
        const float mn = fmaxf(m_run, pm);
        const float alpha = __expf(m_run - mn);
        m_run = mn;
        float rs = 0.f;
#pragma unroll
        for (int t = 0; t < 4; ++t)
#pragma unroll
            for (int i = 0; i < 4; ++i) {
                float p = __expf(st[t][i] - mn);
                st[t][i] = p;
                rs += p;
            }
        rs += __shfl_xor(rs, 16, 64);
        rs += __shfl_xor(rs, 32, 64);
        l_run = l_run * alpha + rs;
#pragma unroll
        for (int n = 0; n < 4; ++n)
#pragma unroll
            for (int i = 0; i < 4; ++i) oa[n][i] *= alpha;

        // P[q=lr][kv] -> per-wave LDS, packed 8B writes (kv = t*16+lg*4+i contiguous in i)
#pragma unroll
        for (int t = 0; t < 4; ++t) {
            us4 pk;
#pragma unroll
            for (int i = 0; i < 4; ++i) pk[i] = f2bf(st[t][i]);
            *(us4*)&Pl[wid][lr][t * 16 + lg * 4] = pk;
        }
        short8 pf0 = *(const short8*)&Pl[wid][lr][lg * 8];
        short8 pf1 = *(const short8*)&Pl[wid][lr][32 + lg * 8];

        // O^T += V^T · P^T
#pragma unroll
        for (int n = 0; n < 4; ++n) {
            oa[n] = __builtin_amdgcn_mfma_f32_16x16x32_bf16(vf0[n], pf0, oa[n], 0, 0, 0);
            oa[n] = __builtin_amdgcn_mfma_f32_16x16x32_bf16(vf1[n], pf1, oa[n], 0, 0, 0);
        }
    }

    const int b = bh >> 4, h = bh & 15;
    const int s = q0 + wid * 16 + lr;
    const float scl = 0.125f / l_run;   // softmax BEFORE scaling -> /8 here
#pragma unroll
    for (int n = 0; n < 4; ++n) {
        us4 pk;
#pragma unroll
        for (int i = 0; i < 4; ++i) pk[i] = f2bf(oa[n][i] * scl);
        *(us4*)&o[(((size_t)b * NS + s) * NH + h) * ND + n * 16 + lg * 4] = pk;
    }
}

extern "C" void kernel_launch(void* const* d_in, const int* in_sizes, int n_in,
                              void* d_out, int out_size, void* d_ws, size_t ws_size,
                              hipStream_t stream) {
    (void)in_sizes; (void)n_in; (void)out_size; (void)ws_size;
    const float* values  = (const float*)d_in[0];
    const float* keys    = (const float*)d_in[1];
    const float* queries = (const float*)d_in[2];
    const float* Wv = (const float*)d_in[3];
    const float* Wk = (const float*)d_in[4];
    const float* Wq = (const float*)d_in[5];
    const float* Wo = (const float*)d_in[6];
    const float* bo = (const float*)d_in[7];

    uint8_t* ws = (uint8_t*)d_ws;
    const size_t MB = (size_t)1 << 20;
    unsigned short* wvb = (unsigned short*)(ws + 0 * MB);
    unsigned short* wkb = (unsigned short*)(ws + 2 * MB);
    unsigned short* wqb = (unsigned short*)(ws + 4 * MB);
    unsigned short* wob = (unsigned short*)(ws + 6 * MB);
    unsigned short* qb  = (unsigned short*)(ws + 8 * MB);   // [B,H,S,D] bf16, 16 MB
    unsigned short* kb  = (unsigned short*)(ws + 24 * MB);  // [B,H,S,D] bf16
    unsigned short* vtb = (unsigned short*)(ws + 40 * MB);  // [B,H,D,S] bf16 (transposed V)
    unsigned short* ab  = (unsigned short*)(ws + 56 * MB);  // [B,S,H,D] bf16, 16 MB

    cvt_w_kernel<<<1024, 256, 0, stream>>>(Wv, wvb);
    cvt_w_kernel<<<1024, 256, 0, stream>>>(Wk, wkb);
    cvt_w_kernel<<<1024, 256, 0, stream>>>(Wq, wqb);

    dim3 gg(64, 8);  // (M/128, N/128)
    gemm_bt<1, 0><<<gg, 256, 0, stream>>>(queries, wqb, qb,  nullptr);
    gemm_bt<1, 0><<<gg, 256, 0, stream>>>(keys,    wkb, kb,  nullptr);
    gemm_bt<1, 2><<<gg, 256, 0, stream>>>(values,  wvb, vtb, nullptr);

    cvt_w_kernel<<<1024, 256, 0, stream>>>(Wo, wob);

    attn_kernel<<<dim3(32, 64), 256, 0, stream>>>(qb, kb, vtb, ab);

    gemm_bt<0, 1><<<gg, 256, 0, stream>>>(ab, wob, d_out, bo);
}